// Round 1
// baseline (1374.913 us; speedup 1.0000x reference)
//
#include <hip/hip_runtime.h>
#include <math.h>

#define Bb 2
#define Nn 32768
#define Cc 128
#define Ff 128
#define Dd 3
#define LL 4
#define SK 64
#define TWOPI 6.283185307179586f

// ---------------- in projection: hf[b,n,c] = sum_i a[b,n,i]*w[i,c] + bias[c]
__global__ __launch_bounds__(256) void in_proj(const float* __restrict__ a,
                                               const float* __restrict__ w,
                                               const float* __restrict__ bias,
                                               float* __restrict__ hf) {
    int idx = blockIdx.x * 256 + threadIdx.x;   // b*N*C + n*C + c
    int c = idx & (Cc - 1);
    int bn = idx >> 7;
    const float* ap = a + bn * 4;
    float s = bias[c];
#pragma unroll
    for (int i = 0; i < 4; ++i) s += ap[i] * w[i * Cc + c];
    hf[idx] = s;
}

// ---------------- forward transform partials:
// Spart[b,h,sk,c,f] = sum_{n in chunk sk} hf[b,n,c] * trig_h(2pi * x[b,n]·k[f])
// h=0 -> cos, h=1 -> sin
__global__ __launch_bounds__(256) void fwd_kernel(const float* __restrict__ hf,
                                                  const float* __restrict__ x,
                                                  const float* __restrict__ freqs,
                                                  float* __restrict__ Spart) {
    __shared__ float hs[16][Cc];    // [k][c]
    __shared__ float ts[16][Ff];    // [k][f]
    __shared__ float ks[Ff][3];

    int sk = blockIdx.x, h = blockIdx.y, b = blockIdx.z;
    int tid = threadIdx.x;
    int ty = tid >> 4, tx = tid & 15;

    for (int i = tid; i < Ff * 3; i += 256) ks[i / 3][i % 3] = freqs[i];

    float acc[8][8];
#pragma unroll
    for (int i = 0; i < 8; ++i)
#pragma unroll
        for (int j = 0; j < 8; ++j) acc[i][j] = 0.0f;

    const int n0 = sk * (Nn / SK);   // 512-point chunk

    for (int kt = 0; kt < Nn / SK; kt += 16) {
        __syncthreads();
        // stage hf tile (16 rows x 128 c), coalesced
        for (int i = tid; i < 16 * Cc; i += 256) {
            int k = i >> 7, c = i & 127;
            hs[k][c] = hf[(b * Nn + n0 + kt + k) * Cc + c];
        }
        // compute trig tile (16 rows x 128 f)
        for (int i = tid; i < 16 * Ff; i += 256) {
            int k = i >> 7, f = i & 127;
            const float* xp = x + (size_t)(b * Nn + n0 + kt + k) * 3;
            float t = xp[0] * ks[f][0] + xp[1] * ks[f][1] + xp[2] * ks[f][2];
            float ang = TWOPI * t;
            ts[k][f] = (h == 0) ? __cosf(ang) : __sinf(ang);
        }
        __syncthreads();
#pragma unroll
        for (int k = 0; k < 16; ++k) {
            float av[8], bv[8];
#pragma unroll
            for (int i = 0; i < 8; ++i) av[i] = hs[k][ty * 8 + i];
#pragma unroll
            for (int j = 0; j < 8; ++j) bv[j] = ts[k][tx * 8 + j];
#pragma unroll
            for (int i = 0; i < 8; ++i)
#pragma unroll
                for (int j = 0; j < 8; ++j) acc[i][j] += av[i] * bv[j];
        }
    }

    float* op = Spart + (size_t)(((b * 2 + h) * SK + sk)) * (Cc * Ff);
#pragma unroll
    for (int i = 0; i < 8; ++i)
#pragma unroll
        for (int j = 0; j < 8; ++j)
            op[(ty * 8 + i) * Ff + tx * 8 + j] = acc[i][j];
}

// ---------------- reduce split-K partials: S[b,h,c,f] = sum_sk Spart
__global__ __launch_bounds__(256) void reduce_kernel(const float* __restrict__ Spart,
                                                     float* __restrict__ S) {
    int idx = blockIdx.x * 256 + threadIdx.x;     // over B*2*C*F = 65536
    int bh = idx >> 14, cf = idx & 16383;
    const float* p = Spart + (size_t)bh * SK * 16384 + cf;
    float s = 0.0f;
#pragma unroll 8
    for (int k = 0; k < SK; ++k) s += p[(size_t)k * 16384];
    S[idx] = s;
}

// ---------------- per-frequency channel mixing (c-split partial, atomicAdd):
// Gre[b,o,f] = (1/N) sum_c  Sc*Wre + Ss*Wim
// Gmi[b,o,f] = (1/N) sum_c  Ss*Wre - Sc*Wim      (= -Im(G))
__global__ __launch_bounds__(256) void mix_kernel(const float* __restrict__ S,
                                                  const float* __restrict__ Wre,
                                                  const float* __restrict__ Wim,
                                                  float* __restrict__ G) {
    int f0 = blockIdx.x * 16, c0 = blockIdx.y * 16, b = blockIdx.z;
    int tid = threadIdx.x;
    int fl = tid & 15, og = tid >> 4;   // og in 0..15
    int f = f0 + fl;
    const float* Sc = S + (size_t)(b * 2 + 0) * 16384;
    const float* Ss = S + (size_t)(b * 2 + 1) * 16384;

    float gre[8], gmi[8];
#pragma unroll
    for (int j = 0; j < 8; ++j) { gre[j] = 0.0f; gmi[j] = 0.0f; }

    for (int c = c0; c < c0 + 16; ++c) {
        float sc = Sc[c * Ff + f];
        float ss = Ss[c * Ff + f];
#pragma unroll
        for (int j = 0; j < 8; ++j) {
            int o = og + j * 16;
            float wr = Wre[((size_t)c * Cc + o) * Ff + f];
            float wi = Wim[((size_t)c * Cc + o) * Ff + f];
            gre[j] += sc * wr + ss * wi;
            gmi[j] += ss * wr - sc * wi;
        }
    }
    const float inv = 1.0f / (float)Nn;
#pragma unroll
    for (int j = 0; j < 8; ++j) {
        int o = og + j * 16;
        atomicAdd(&G[(size_t)(b * 2 + 0) * 16384 + o * Ff + f], gre[j] * inv);
        atomicAdd(&G[(size_t)(b * 2 + 1) * 16384 + o * Ff + f], gmi[j] * inv);
    }
}

// ---------------- inverse evaluation + gelu (in-place into hf):
// hf[b,n,o] = gelu( sum_f cos(ang)*Gre[o,f] + sin(ang)*Gmi[o,f] ),  ang=2pi*pts[n]·k[f]
__global__ __launch_bounds__(256) void inv_kernel(const float* __restrict__ G,
                                                  const float* __restrict__ pts,
                                                  const float* __restrict__ freqs,
                                                  float* __restrict__ hf) {
    __shared__ float At[32][Cc];        // [kk][n]   trig
    __shared__ float Bt[32][129];       // [kk][o]   G, padded
    __shared__ float ks[Ff][3];
    __shared__ float xs[Cc][3];

    int n0 = blockIdx.x * 128, b = blockIdx.y;
    int tid = threadIdx.x;
    int ty = tid >> 4, tx = tid & 15;

    for (int i = tid; i < Ff * 3; i += 256) ks[i / 3][i % 3] = freqs[i];
    for (int i = tid; i < 128 * 3; i += 256) xs[i / 3][i % 3] = pts[(size_t)(b * Nn + n0) * 3 + i];

    float acc[8][8];
#pragma unroll
    for (int i = 0; i < 8; ++i)
#pragma unroll
        for (int j = 0; j < 8; ++j) acc[i][j] = 0.0f;

    for (int k0 = 0; k0 < 2 * Ff; k0 += 32) {
        __syncthreads();
        // trig tile: At[kk][n]
        for (int i = tid; i < 32 * 128; i += 256) {
            int kk = i >> 7, n = i & 127;
            int kg = k0 + kk;
            int f = kg & 127;
            float t = xs[n][0] * ks[f][0] + xs[n][1] * ks[f][1] + xs[n][2] * ks[f][2];
            float ang = TWOPI * t;
            At[kk][n] = (kg < 128) ? __cosf(ang) : __sinf(ang);
        }
        // G tile: Bt[kk][o] = (kg<128 ? Gre : Gmi)[b][o][f]
        for (int i = tid; i < 32 * 128; i += 256) {
            int kk = i & 31, o = i >> 5;     // consecutive tid -> consecutive kk -> coalesced f
            int kg = k0 + kk;
            int f = kg & 127;
            Bt[kk][o] = G[(size_t)(b * 2 + (kg >> 7)) * 16384 + o * Ff + f];
        }
        __syncthreads();
#pragma unroll
        for (int kk = 0; kk < 32; ++kk) {
            float av[8], bv[8];
#pragma unroll
            for (int i = 0; i < 8; ++i) av[i] = At[kk][ty * 8 + i];
#pragma unroll
            for (int j = 0; j < 8; ++j) bv[j] = Bt[kk][tx * 8 + j];
#pragma unroll
            for (int i = 0; i < 8; ++i)
#pragma unroll
                for (int j = 0; j < 8; ++j) acc[i][j] += av[i] * bv[j];
        }
    }

    // epilogue: gelu (tanh approximation, matching jax.nn.gelu default) + store
#pragma unroll
    for (int i = 0; i < 8; ++i) {
#pragma unroll
        for (int j = 0; j < 8; ++j) {
            float v = acc[i][j];
            float u = 0.7978845608028654f * (v + 0.044715f * v * v * v);
            float g = 0.5f * v * (1.0f + tanhf(u));
            hf[(size_t)(b * Nn + n0 + ty * 8 + i) * Cc + tx * 8 + j] = g;
        }
    }
}

// ---------------- out projection: u[b,n,o] = sum_c hf[b,n,c]*w[c,o] + bias[o]
__global__ __launch_bounds__(256) void out_proj(const float* __restrict__ hf,
                                                const float* __restrict__ w,
                                                const float* __restrict__ bias,
                                                float* __restrict__ u) {
    int tid = threadIdx.x;
    int wv = tid >> 6, ln = tid & 63;
    size_t row = (size_t)blockIdx.x * 4 + wv;    // b*N + n
    const float* hp = hf + row * Cc;
    float h0 = hp[ln], h1 = hp[ln + 64];
    float s0 = h0 * w[ln * 2 + 0] + h1 * w[(ln + 64) * 2 + 0];
    float s1 = h0 * w[ln * 2 + 1] + h1 * w[(ln + 64) * 2 + 1];
#pragma unroll
    for (int off = 32; off > 0; off >>= 1) {
        s0 += __shfl_down(s0, off);
        s1 += __shfl_down(s1, off);
    }
    if (ln == 0) {
        u[row * 2 + 0] = s0 + bias[0];
        u[row * 2 + 1] = s1 + bias[1];
    }
}

extern "C" void kernel_launch(void* const* d_in, const int* in_sizes, int n_in,
                              void* d_out, int out_size, void* d_ws, size_t ws_size,
                              hipStream_t stream) {
    const float* a        = (const float*)d_in[0];
    const float* x        = (const float*)d_in[1];
    const float* y        = (const float*)d_in[2];
    const float* fc_in_w  = (const float*)d_in[3];
    const float* fc_in_b  = (const float*)d_in[4];
    const float* freqs    = (const float*)d_in[5];
    const float* w_real   = (const float*)d_in[6];
    const float* w_imag   = (const float*)d_in[7];
    const float* fc_out_w = (const float*)d_in[8];
    const float* fc_out_b = (const float*)d_in[9];
    float* out = (float*)d_out;

    float* ws    = (float*)d_ws;
    float* hf    = ws;                       // B*N*C           = 8,388,608 floats
    float* Spart = hf + (size_t)Bb * Nn * Cc;        // B*2*SK*C*F = 4,194,304
    float* S     = Spart + (size_t)Bb * 2 * SK * Cc * Ff;  // B*2*C*F = 65,536
    float* G     = S + (size_t)Bb * 2 * Cc * Ff;           // B*2*C*F = 65,536

    in_proj<<<(Bb * Nn * Cc) / 256, 256, 0, stream>>>(a, fc_in_w, fc_in_b, hf);

    for (int l = 0; l < LL; ++l) {
        const float* k   = freqs  + (size_t)l * Ff * Dd;
        const float* Wre = w_real + (size_t)l * Cc * Cc * Ff;
        const float* Wim = w_imag + (size_t)l * Cc * Cc * Ff;
        const float* pts = (l < LL - 1) ? x : y;

        fwd_kernel<<<dim3(SK, 2, Bb), 256, 0, stream>>>(hf, x, k, Spart);
        reduce_kernel<<<(Bb * 2 * Cc * Ff) / 256, 256, 0, stream>>>(Spart, S);
        hipMemsetAsync(G, 0, (size_t)Bb * 2 * Cc * Ff * sizeof(float), stream);
        mix_kernel<<<dim3(Ff / 16, Cc / 16, Bb), 256, 0, stream>>>(S, Wre, Wim, G);
        inv_kernel<<<dim3(Nn / 128, Bb), 256, 0, stream>>>(G, pts, k, hf);
    }

    out_proj<<<(Bb * Nn) / 4, 256, 0, stream>>>(hf, fc_out_w, fc_out_b, out);
}

// Round 2
// 568.596 us; speedup vs baseline: 2.4181x; 2.4181x over previous
//
#include <hip/hip_runtime.h>
#include <math.h>

#define Bb 2
#define Nn 32768
#define Cc 128
#define Ff 128
#define Dd 3
#define LL 4
#define TWOPI 6.283185307179586f
#define TP 40   // LDS tile row pitch (ushorts): 80 B = 20 banks -> conflict-free b128 frags

typedef __attribute__((ext_vector_type(8))) short short8;
typedef __attribute__((ext_vector_type(4))) float float4v;
typedef unsigned short ushort_t;
typedef unsigned int uint_t;

__device__ inline ushort_t f2bf(float v) {
    union { float f; uint_t u; } x; x.f = v;
    uint_t r = x.u + 0x7fffu + ((x.u >> 16) & 1u);
    return (ushort_t)(r >> 16);
}
__device__ inline float bf2f(ushort_t s) {
    union { uint_t u; float f; } x; x.u = ((uint_t)s) << 16;
    return x.f;
}

// ---------------- in projection: hf[b,n,c] = sum_i a[b,n,i]*w[i,c] + bias[c]
__global__ __launch_bounds__(256) void in_proj(const float* __restrict__ a,
                                               const float* __restrict__ w,
                                               const float* __restrict__ bias,
                                               float* __restrict__ hf) {
    int idx = blockIdx.x * 256 + threadIdx.x;
    int c = idx & (Cc - 1);
    int bn = idx >> 7;
    const float* ap = a + bn * 4;
    float s = bias[c];
#pragma unroll
    for (int i = 0; i < 4; ++i) s += ap[i] * w[i * Cc + c];
    hf[idx] = s;
}

// ---------------- forward transform (MFMA, hi/lo bf16 split):
// Spart[b,h,sk][c][f] = sum_{n in chunk} hf[b,n,c] * trig_h(2pi x[b,n]·k[f])
__global__ __launch_bounds__(256) void fwd_mfma(const float* __restrict__ hf,
                                                const float* __restrict__ x,
                                                const float* __restrict__ freqs,
                                                float* __restrict__ Spart) {
    __shared__ __align__(16) ushort_t Ah[128][TP], Al[128][TP];
    __shared__ __align__(16) ushort_t Bh[128][TP], Bl[128][TP];
    __shared__ float ks[128][3];

    const int sk = blockIdx.x, h = blockIdx.y, b = blockIdx.z;
    const int SKn = gridDim.x;
    const int chunk = Nn / SKn;
    const int n0 = sk * chunk;
    const int tid = threadIdx.x;
    for (int i = tid; i < 384; i += 256) ((float*)ks)[i] = freqs[i];

    const int lane = tid & 63, wave = tid >> 6;
    const int wr = (wave >> 1) * 64, wc = (wave & 1) * 64;
    const int fr = lane & 15, kg = lane >> 4;

    float4v acc[4][4];
#pragma unroll
    for (int mi = 0; mi < 4; ++mi)
#pragma unroll
        for (int ni = 0; ni < 4; ++ni) acc[mi][ni] = (float4v){0.f, 0.f, 0.f, 0.f};

    for (int kt = 0; kt < chunk; kt += 32) {
        __syncthreads();
        // stage A = hf^T tile: Ah/Al[c][k], k contiguous (pairs packed as b32)
#pragma unroll
        for (int i = 0; i < 8; ++i) {
            int p = tid + i * 256;
            int c = p & 127, nl = (p >> 7) * 2;
            const float* hp = hf + ((size_t)((b << 15) + n0 + kt + nl)) * 128 + c;
            float v0 = hp[0], v1 = hp[128];
            ushort_t h0 = f2bf(v0), h1 = f2bf(v1);
            ushort_t l0 = f2bf(v0 - bf2f(h0)), l1 = f2bf(v1 - bf2f(h1));
            *(uint_t*)&Ah[c][nl] = (uint_t)h0 | ((uint_t)h1 << 16);
            *(uint_t*)&Al[c][nl] = (uint_t)l0 | ((uint_t)l1 << 16);
        }
        // stage B = trig tile: Bh/Bl[f][k]
#pragma unroll
        for (int i = 0; i < 8; ++i) {
            int p = tid + i * 256;
            int f = p & 127, nl = (p >> 7) * 2;
            const float* xp = x + ((size_t)((b << 15) + n0 + kt + nl)) * 3;
            float k0v = ks[f][0], k1v = ks[f][1], k2v = ks[f][2];
            float t0 = xp[0] * k0v + xp[1] * k1v + xp[2] * k2v;
            float t1 = xp[3] * k0v + xp[4] * k1v + xp[5] * k2v;
            float a0 = TWOPI * t0, a1 = TWOPI * t1;
            float v0 = h ? __sinf(a0) : __cosf(a0);
            float v1 = h ? __sinf(a1) : __cosf(a1);
            ushort_t h0 = f2bf(v0), h1 = f2bf(v1);
            ushort_t l0 = f2bf(v0 - bf2f(h0)), l1 = f2bf(v1 - bf2f(h1));
            *(uint_t*)&Bh[f][nl] = (uint_t)h0 | ((uint_t)h1 << 16);
            *(uint_t*)&Bl[f][nl] = (uint_t)l0 | ((uint_t)l1 << 16);
        }
        __syncthreads();
        short8 bh[4], bl[4];
#pragma unroll
        for (int ni = 0; ni < 4; ++ni) {
            bh[ni] = *(const short8*)&Bh[wc + ni * 16 + fr][kg * 8];
            bl[ni] = *(const short8*)&Bl[wc + ni * 16 + fr][kg * 8];
        }
#pragma unroll
        for (int mi = 0; mi < 4; ++mi) {
            short8 ah = *(const short8*)&Ah[wr + mi * 16 + fr][kg * 8];
            short8 al = *(const short8*)&Al[wr + mi * 16 + fr][kg * 8];
#pragma unroll
            for (int ni = 0; ni < 4; ++ni) {
                acc[mi][ni] = __builtin_amdgcn_mfma_f32_16x16x32_bf16(ah, bh[ni], acc[mi][ni], 0, 0, 0);
                acc[mi][ni] = __builtin_amdgcn_mfma_f32_16x16x32_bf16(ah, bl[ni], acc[mi][ni], 0, 0, 0);
                acc[mi][ni] = __builtin_amdgcn_mfma_f32_16x16x32_bf16(al, bh[ni], acc[mi][ni], 0, 0, 0);
            }
        }
    }

    float* op = Spart + ((size_t)((b * 2 + h) * SKn + sk)) * 16384;
#pragma unroll
    for (int mi = 0; mi < 4; ++mi)
#pragma unroll
        for (int ni = 0; ni < 4; ++ni)
#pragma unroll
            for (int r = 0; r < 4; ++r) {
                int c = wr + mi * 16 + kg * 4 + r;   // D row
                int f = wc + ni * 16 + fr;           // D col
                op[c * 128 + f] = acc[mi][ni][r];
            }
}

// ---------------- reduce split-K partials
__global__ __launch_bounds__(256) void reduce_kernel(const float* __restrict__ Spart,
                                                     float* __restrict__ S, int SKn) {
    int idx = blockIdx.x * 256 + threadIdx.x;
    int bh = idx >> 14, cf = idx & 16383;
    const float* p = Spart + (size_t)bh * SKn * 16384 + cf;
    float s = 0.0f;
    for (int k = 0; k < SKn; ++k) s += p[(size_t)k * 16384];
    S[idx] = s;
}

// ---------------- per-frequency channel mixing (c-split, atomicAdd)
__global__ __launch_bounds__(256) void mix_kernel(const float* __restrict__ S,
                                                  const float* __restrict__ Wre,
                                                  const float* __restrict__ Wim,
                                                  float* __restrict__ G) {
    int f0 = blockIdx.x * 16, c0 = blockIdx.y * 16, b = blockIdx.z;
    int tid = threadIdx.x;
    int fl = tid & 15, og = tid >> 4;
    int f = f0 + fl;
    const float* Sc = S + (size_t)(b * 2 + 0) * 16384;
    const float* Ss = S + (size_t)(b * 2 + 1) * 16384;

    float gre[8], gmi[8];
#pragma unroll
    for (int j = 0; j < 8; ++j) { gre[j] = 0.0f; gmi[j] = 0.0f; }

    for (int c = c0; c < c0 + 16; ++c) {
        float sc = Sc[c * Ff + f];
        float ss = Ss[c * Ff + f];
#pragma unroll
        for (int j = 0; j < 8; ++j) {
            int o = og + j * 16;
            float wr = Wre[((size_t)c * Cc + o) * Ff + f];
            float wi = Wim[((size_t)c * Cc + o) * Ff + f];
            gre[j] += sc * wr + ss * wi;
            gmi[j] += ss * wr - sc * wi;
        }
    }
    const float inv = 1.0f / (float)Nn;
#pragma unroll
    for (int j = 0; j < 8; ++j) {
        int o = og + j * 16;
        atomicAdd(&G[(size_t)(b * 2 + 0) * 16384 + o * Ff + f], gre[j] * inv);
        atomicAdd(&G[(size_t)(b * 2 + 1) * 16384 + o * Ff + f], gmi[j] * inv);
    }
}

// ---------------- inverse evaluation + gelu (MFMA, hi/lo bf16 split)
// hf[b,n,o] = gelu( sum_{h,f} trig_h(2pi pts·k[f]) * G[b,h,o,f] )
__global__ __launch_bounds__(256) void inv_mfma(const float* __restrict__ G,
                                                const float* __restrict__ pts,
                                                const float* __restrict__ freqs,
                                                float* __restrict__ hf) {
    __shared__ __align__(16) ushort_t Ah[128][TP], Al[128][TP];
    __shared__ __align__(16) ushort_t Bh[128][TP], Bl[128][TP];
    __shared__ float ks[128][3];
    __shared__ float xs[128][3];

    const int nt = blockIdx.x, b = blockIdx.y;
    const int n0 = nt * 128;
    const int tid = threadIdx.x;
    for (int i = tid; i < 384; i += 256) {
        ((float*)ks)[i] = freqs[i];
        ((float*)xs)[i] = pts[((size_t)(b << 15) + n0) * 3 + i];
    }

    const int lane = tid & 63, wave = tid >> 6;
    const int wr = (wave >> 1) * 64, wc = (wave & 1) * 64;
    const int fr = lane & 15, kg = lane >> 4;

    float4v acc[4][4];
#pragma unroll
    for (int mi = 0; mi < 4; ++mi)
#pragma unroll
        for (int ni = 0; ni < 4; ++ni) acc[mi][ni] = (float4v){0.f, 0.f, 0.f, 0.f};

    for (int kt = 0; kt < 8; ++kt) {
        __syncthreads();
        const int h = kt >> 2, f0 = (kt & 3) * 32;
        // A = trig tile [n][k]
#pragma unroll
        for (int i = 0; i < 8; ++i) {
            int p = tid + i * 256;
            int n = p >> 4, kl = (p & 15) * 2;
            int f = f0 + kl;
            float x0 = xs[n][0], x1 = xs[n][1], x2 = xs[n][2];
            float t0 = x0 * ks[f][0] + x1 * ks[f][1] + x2 * ks[f][2];
            float t1 = x0 * ks[f + 1][0] + x1 * ks[f + 1][1] + x2 * ks[f + 1][2];
            float a0 = TWOPI * t0, a1 = TWOPI * t1;
            float v0 = h ? __sinf(a0) : __cosf(a0);
            float v1 = h ? __sinf(a1) : __cosf(a1);
            ushort_t h0 = f2bf(v0), h1 = f2bf(v1);
            ushort_t l0 = f2bf(v0 - bf2f(h0)), l1 = f2bf(v1 - bf2f(h1));
            *(uint_t*)&Ah[n][kl] = (uint_t)h0 | ((uint_t)h1 << 16);
            *(uint_t*)&Al[n][kl] = (uint_t)l0 | ((uint_t)l1 << 16);
        }
        // B = G slice [o][k] (k = f contiguous in G's native layout)
#pragma unroll
        for (int i = 0; i < 8; ++i) {
            int p = tid + i * 256;
            int o = p >> 4, kl = (p & 15) * 2;
            const float* gp = G + (((size_t)(b * 2 + h) * 128 + o) * 128 + f0 + kl);
            float g0 = gp[0], g1 = gp[1];
            ushort_t h0 = f2bf(g0), h1 = f2bf(g1);
            ushort_t l0 = f2bf(g0 - bf2f(h0)), l1 = f2bf(g1 - bf2f(h1));
            *(uint_t*)&Bh[o][kl] = (uint_t)h0 | ((uint_t)h1 << 16);
            *(uint_t*)&Bl[o][kl] = (uint_t)l0 | ((uint_t)l1 << 16);
        }
        __syncthreads();
        short8 bh[4], bl[4];
#pragma unroll
        for (int ni = 0; ni < 4; ++ni) {
            bh[ni] = *(const short8*)&Bh[wc + ni * 16 + fr][kg * 8];
            bl[ni] = *(const short8*)&Bl[wc + ni * 16 + fr][kg * 8];
        }
#pragma unroll
        for (int mi = 0; mi < 4; ++mi) {
            short8 ah = *(const short8*)&Ah[wr + mi * 16 + fr][kg * 8];
            short8 al = *(const short8*)&Al[wr + mi * 16 + fr][kg * 8];
#pragma unroll
            for (int ni = 0; ni < 4; ++ni) {
                acc[mi][ni] = __builtin_amdgcn_mfma_f32_16x16x32_bf16(ah, bh[ni], acc[mi][ni], 0, 0, 0);
                acc[mi][ni] = __builtin_amdgcn_mfma_f32_16x16x32_bf16(ah, bl[ni], acc[mi][ni], 0, 0, 0);
                acc[mi][ni] = __builtin_amdgcn_mfma_f32_16x16x32_bf16(al, bh[ni], acc[mi][ni], 0, 0, 0);
            }
        }
    }

    // epilogue: gelu (tanh approx, matches jax.nn.gelu) + store
#pragma unroll
    for (int mi = 0; mi < 4; ++mi)
#pragma unroll
        for (int ni = 0; ni < 4; ++ni)
#pragma unroll
            for (int r = 0; r < 4; ++r) {
                int n = wr + mi * 16 + kg * 4 + r;
                int o = wc + ni * 16 + fr;
                float v = acc[mi][ni][r];
                float u = 0.7978845608028654f * (v + 0.044715f * v * v * v);
                float g = 0.5f * v * (1.0f + tanhf(u));
                hf[((size_t)(b << 15) + n0 + n) * 128 + o] = g;
            }
}

// ---------------- out projection
__global__ __launch_bounds__(256) void out_proj(const float* __restrict__ hf,
                                                const float* __restrict__ w,
                                                const float* __restrict__ bias,
                                                float* __restrict__ u) {
    int tid = threadIdx.x;
    int wv = tid >> 6, ln = tid & 63;
    size_t row = (size_t)blockIdx.x * 4 + wv;
    const float* hp = hf + row * Cc;
    float h0 = hp[ln], h1 = hp[ln + 64];
    float s0 = h0 * w[ln * 2 + 0] + h1 * w[(ln + 64) * 2 + 0];
    float s1 = h0 * w[ln * 2 + 1] + h1 * w[(ln + 64) * 2 + 1];
#pragma unroll
    for (int off = 32; off > 0; off >>= 1) {
        s0 += __shfl_down(s0, off);
        s1 += __shfl_down(s1, off);
    }
    if (ln == 0) {
        u[row * 2 + 0] = s0 + bias[0];
        u[row * 2 + 1] = s1 + bias[1];
    }
}

extern "C" void kernel_launch(void* const* d_in, const int* in_sizes, int n_in,
                              void* d_out, int out_size, void* d_ws, size_t ws_size,
                              hipStream_t stream) {
    const float* a        = (const float*)d_in[0];
    const float* x        = (const float*)d_in[1];
    const float* y        = (const float*)d_in[2];
    const float* fc_in_w  = (const float*)d_in[3];
    const float* fc_in_b  = (const float*)d_in[4];
    const float* freqs    = (const float*)d_in[5];
    const float* w_real   = (const float*)d_in[6];
    const float* w_imag   = (const float*)d_in[7];
    const float* fc_out_w = (const float*)d_in[8];
    const float* fc_out_b = (const float*)d_in[9];
    float* out = (float*)d_out;

    const size_t hfN = (size_t)Bb * Nn * Cc;                    // 8,388,608
    const size_t need128 = (hfN + (size_t)Bb * 2 * 128 * Cc * Ff + 2 * 65536) * sizeof(float);
    const int SKn = (ws_size >= need128) ? 128 : 64;            // split-K chunks

    float* ws    = (float*)d_ws;
    float* hf    = ws;
    float* Spart = hf + hfN;
    float* S     = Spart + (size_t)Bb * 2 * SKn * Cc * Ff;
    float* G     = S + (size_t)Bb * 2 * Cc * Ff;

    in_proj<<<(Bb * Nn * Cc) / 256, 256, 0, stream>>>(a, fc_in_w, fc_in_b, hf);

    for (int l = 0; l < LL; ++l) {
        const float* k   = freqs  + (size_t)l * Ff * Dd;
        const float* Wre = w_real + (size_t)l * Cc * Cc * Ff;
        const float* Wim = w_imag + (size_t)l * Cc * Cc * Ff;
        const float* pts = (l < LL - 1) ? x : y;

        fwd_mfma<<<dim3(SKn, 2, Bb), 256, 0, stream>>>(hf, x, k, Spart);
        reduce_kernel<<<(Bb * 2 * Cc * Ff) / 256, 256, 0, stream>>>(Spart, S, SKn);
        hipMemsetAsync(G, 0, (size_t)Bb * 2 * Cc * Ff * sizeof(float), stream);
        mix_kernel<<<dim3(Ff / 16, Cc / 16, Bb), 256, 0, stream>>>(S, Wre, Wim, G);
        inv_mfma<<<dim3(Nn / 128, Bb), 256, 0, stream>>>(G, pts, k, hf);
    }

    out_proj<<<(Bb * Nn) / 4, 256, 0, stream>>>(hf, fc_out_w, fc_out_b, out);
}

// Round 3
// 456.072 us; speedup vs baseline: 3.0147x; 1.2467x over previous
//
#include <hip/hip_runtime.h>
#include <math.h>

#define Bb 2
#define Nn 32768
#define Cc 128
#define Ff 128
#define LL 4
#define SKN 128
#define TWOPI 6.283185307179586f
#define TP 40   // LDS row pitch (ushorts): 80 B = 20 banks -> conflict-free b128 frag reads

typedef __attribute__((ext_vector_type(8))) short short8;
typedef __attribute__((ext_vector_type(4))) float float4v;
typedef unsigned short ushort_t;
typedef unsigned int uint_t;

union frag_cast { short8 s; uint_t u[4]; };

__device__ inline uint_t asu(float f) { union { float f; uint_t u; } x; x.f = f; return x.u; }
__device__ inline float asf(uint_t u) { union { uint_t u; float f; } x; x.u = u; return x.f; }
// pack: low16 = bf16-trunc(v0), high16 = bf16-trunc(v1)
__device__ inline uint_t pack_hi(float v0, float v1) { return (asu(v0) >> 16) | (asu(v1) & 0xffff0000u); }
// exact residual after bf16 truncation (Sterbenz: fits fp32 exactly)
__device__ inline float resid(float v) { return v - asf(asu(v) & 0xffff0000u); }

// ---------------- in projection: hf[b,n,c] = sum_i a[b,n,i]*w[i,c] + bias[c]
__global__ __launch_bounds__(256) void in_proj(const float* __restrict__ a,
                                               const float* __restrict__ w,
                                               const float* __restrict__ bias,
                                               float* __restrict__ hf) {
    int idx = blockIdx.x * 256 + threadIdx.x;
    int c = idx & (Cc - 1);
    int bn = idx >> 7;
    const float* ap = a + bn * 4;
    float s = bias[c];
#pragma unroll
    for (int i = 0; i < 4; ++i) s += ap[i] * w[i * Cc + c];
    hf[idx] = s;
}

// ---------------- forward transform, h-fused (MFMA, trunc hi/lo bf16 split):
// Spart[b,h,sk][c][f] = sum_{n in chunk} hf[b,n,c] * trig_h(2pi x[b,n]·k[f])
__global__ __launch_bounds__(512) void fwd_mfma(const float* __restrict__ hf,
                                                const float* __restrict__ x,
                                                const float* __restrict__ freqs,
                                                float* __restrict__ Spart) {
    __shared__ __align__(16) ushort_t Ah[128][TP], Al[128][TP];
    __shared__ __align__(16) ushort_t Bch[128][TP], Bcl[128][TP], Bsh[128][TP], Bsl[128][TP];

    const int sk = blockIdx.x, b = blockIdx.y;
    const int n0 = sk * (Nn / SKN);          // 256-point chunk
    const int tid = threadIdx.x;
    const int cf = tid & 127, g = tid >> 7;  // staging column (acts as c for A, f for B), n-group

    // this thread's staging frequency (f = cf), hoisted for the whole kernel
    const float kx = freqs[cf * 3 + 0], ky = freqs[cf * 3 + 1], kz = freqs[cf * 3 + 2];

    const int lane = tid & 63, wave = tid >> 6;
    const int h = wave >> 2;                          // waves 0-3: cos, 4-7: sin
    const int wr = ((wave >> 1) & 1) * 64, wc = (wave & 1) * 64;
    const int fr = lane & 15, kg = lane >> 4;

    float4v acc[4][4];
#pragma unroll
    for (int mi = 0; mi < 4; ++mi)
#pragma unroll
        for (int ni = 0; ni < 4; ++ni) acc[mi][ni] = (float4v){0.f, 0.f, 0.f, 0.f};

    const ushort_t (*Bhp)[TP] = h ? Bsh : Bch;
    const ushort_t (*Blp)[TP] = h ? Bsl : Bcl;

    for (int kt = 0; kt < Nn / SKN; kt += 32) {
        __syncthreads();
#pragma unroll
        for (int i = 0; i < 4; ++i) {
            const int nl = g * 8 + i * 2;
            const size_t nrow = (size_t)((b << 15) + n0 + kt + nl);
            // A = hf^T tile (c-column cf, n-pair nl)
            const float* hp = hf + nrow * 128 + cf;
            float v0 = hp[0], v1 = hp[128];
            *(uint_t*)&Ah[cf][nl] = pack_hi(v0, v1);
            *(uint_t*)&Al[cf][nl] = pack_hi(resid(v0), resid(v1));
            // B = trig tiles (f-column cf, n-pair nl), cos and sin share the angle
            const float* xp = x + nrow * 3;
            float t0 = xp[0] * kx + xp[1] * ky + xp[2] * kz;
            float t1 = xp[3] * kx + xp[4] * ky + xp[5] * kz;
            float a0 = TWOPI * t0, a1 = TWOPI * t1;
            float c0 = __cosf(a0), c1 = __cosf(a1);
            float s0 = __sinf(a0), s1 = __sinf(a1);
            *(uint_t*)&Bch[cf][nl] = pack_hi(c0, c1);
            *(uint_t*)&Bcl[cf][nl] = pack_hi(resid(c0), resid(c1));
            *(uint_t*)&Bsh[cf][nl] = pack_hi(s0, s1);
            *(uint_t*)&Bsl[cf][nl] = pack_hi(resid(s0), resid(s1));
        }
        __syncthreads();
        short8 bh[4], bl[4];
#pragma unroll
        for (int ni = 0; ni < 4; ++ni) {
            bh[ni] = *(const short8*)&Bhp[wc + ni * 16 + fr][kg * 8];
            bl[ni] = *(const short8*)&Blp[wc + ni * 16 + fr][kg * 8];
        }
#pragma unroll
        for (int mi = 0; mi < 4; ++mi) {
            short8 ah = *(const short8*)&Ah[wr + mi * 16 + fr][kg * 8];
            short8 al = *(const short8*)&Al[wr + mi * 16 + fr][kg * 8];
#pragma unroll
            for (int ni = 0; ni < 4; ++ni) {
                acc[mi][ni] = __builtin_amdgcn_mfma_f32_16x16x32_bf16(ah, bh[ni], acc[mi][ni], 0, 0, 0);
                acc[mi][ni] = __builtin_amdgcn_mfma_f32_16x16x32_bf16(ah, bl[ni], acc[mi][ni], 0, 0, 0);
                acc[mi][ni] = __builtin_amdgcn_mfma_f32_16x16x32_bf16(al, bh[ni], acc[mi][ni], 0, 0, 0);
            }
        }
    }

    float* op = Spart + ((size_t)((b * 2 + h) * SKN + sk)) * 16384;
#pragma unroll
    for (int mi = 0; mi < 4; ++mi)
#pragma unroll
        for (int ni = 0; ni < 4; ++ni)
#pragma unroll
            for (int r = 0; r < 4; ++r) {
                int c = wr + mi * 16 + kg * 4 + r;
                int f = wc + ni * 16 + fr;
                op[c * 128 + f] = acc[mi][ni][r];
            }
}

// ---------------- reduce split-K partials: S[b,h,c,f] = sum_sk Spart
__global__ __launch_bounds__(256) void reduce_kernel(const float* __restrict__ Spart,
                                                     float* __restrict__ S) {
    int idx = blockIdx.x * 256 + threadIdx.x;
    int bh = idx >> 14, cf = idx & 16383;
    const float* p = Spart + (size_t)bh * SKN * 16384 + cf;
    float s = 0.0f;
#pragma unroll 8
    for (int k = 0; k < SKN; ++k) s += p[(size_t)k * 16384];
    S[idx] = s;
}

// ---------------- channel mixing -> packed bf16 hi/lo G planes, k = 2f+h interleave:
// Gh dword(b,o,f) = bf(Gre)|bf(Gmi)<<16,  Gre = (sum_c Sc*Wre + Ss*Wim)/N,  Gmi = (Ss*Wre - Sc*Wim)/N
__global__ __launch_bounds__(256) void mix_kernel(const float* __restrict__ S,
                                                  const float* __restrict__ Wre,
                                                  const float* __restrict__ Wim,
                                                  uint_t* __restrict__ Gh,
                                                  uint_t* __restrict__ Gl) {
    __shared__ float Ssc[128][32], Sss[128][32];
    const int ot = blockIdx.x, ft = blockIdx.y, b = blockIdx.z;
    const int tid = threadIdx.x;
    const int fl = tid & 31, og = tid >> 5;
    const int o = ot * 8 + og, f = ft * 32 + fl;

    const float* Sc = S + (size_t)(b * 2 + 0) * 16384;
    const float* Ss = S + (size_t)(b * 2 + 1) * 16384;
    for (int i = tid; i < 4096; i += 256) {
        int c = i >> 5, ff = i & 31;
        Ssc[c][ff] = Sc[c * 128 + ft * 32 + ff];
        Sss[c][ff] = Ss[c * 128 + ft * 32 + ff];
    }
    __syncthreads();

    float gre = 0.f, gmi = 0.f;
#pragma unroll 4
    for (int c = 0; c < 128; ++c) {
        float sc = Ssc[c][fl], ss = Sss[c][fl];
        float wr = Wre[((size_t)(c * 128 + o)) * 128 + f];
        float wi = Wim[((size_t)(c * 128 + o)) * 128 + f];
        gre += sc * wr + ss * wi;
        gmi += ss * wr - sc * wi;
    }
    const float invN = 1.0f / (float)Nn;
    gre *= invN; gmi *= invN;
    Gh[(b * 128 + o) * 128 + f] = pack_hi(gre, gmi);
    Gl[(b * 128 + o) * 128 + f] = pack_hi(resid(gre), resid(gmi));
}

// ---------------- inverse evaluation + gelu: barrier-free, zero-LDS MFMA.
// A-fragments (trig) built in registers in A-operand layout; B from packed G planes (L2).
// k = 2f+h: even k -> cos*Gre, odd k -> sin*Gmi.
__global__ __launch_bounds__(256) void inv_mfma(const uint_t* __restrict__ Gh,
                                                const uint_t* __restrict__ Gl,
                                                const float* __restrict__ pts,
                                                const float* __restrict__ freqs,
                                                float* __restrict__ hf) {
    const int n0 = blockIdx.x * 128, b = blockIdx.y;
    const int tid = threadIdx.x;
    const int lane = tid & 63, wave = tid >> 6;
    const int wr = (wave >> 1) * 64, wc = (wave & 1) * 64;
    const int fr = lane & 15, kg = lane >> 4;

    float x0[4], x1[4], x2[4];
#pragma unroll
    for (int mi = 0; mi < 4; ++mi) {
        const float* px = pts + ((size_t)((b << 15) + n0 + wr + mi * 16 + fr)) * 3;
        x0[mi] = px[0]; x1[mi] = px[1]; x2[mi] = px[2];
    }

    float4v acc[4][4];
#pragma unroll
    for (int mi = 0; mi < 4; ++mi)
#pragma unroll
        for (int ni = 0; ni < 4; ++ni) acc[mi][ni] = (float4v){0.f, 0.f, 0.f, 0.f};

    for (int kt = 0; kt < 8; ++kt) {
        const int fbase = kt * 16 + kg * 4;
        // 4 frequencies' (x,y,z), 12 contiguous floats, 16B-aligned
        float4v k0 = *(const float4v*)(freqs + fbase * 3);
        float4v k1 = *(const float4v*)(freqs + fbase * 3 + 4);
        float4v k2 = *(const float4v*)(freqs + fbase * 3 + 8);
        float kxx[4] = {k0[0], k0[3], k1[2], k2[1]};
        float kyy[4] = {k0[1], k1[0], k1[3], k2[2]};
        float kzz[4] = {k0[2], k1[1], k2[0], k2[3]};

        short8 bh[4], bl[4];
#pragma unroll
        for (int ni = 0; ni < 4; ++ni) {
            size_t gi = ((size_t)(b * 128 + wc + ni * 16 + fr)) * 128 + fbase;
            bh[ni] = *(const short8*)(Gh + gi);
            bl[ni] = *(const short8*)(Gl + gi);
        }
#pragma unroll
        for (int mi = 0; mi < 4; ++mi) {
            frag_cast ah, al;
#pragma unroll
            for (int i = 0; i < 4; ++i) {
                float t = x0[mi] * kxx[i] + x1[mi] * kyy[i] + x2[mi] * kzz[i];
                float ang = TWOPI * t;
                float cv = __cosf(ang), sv = __sinf(ang);
                ah.u[i] = pack_hi(cv, sv);
                al.u[i] = pack_hi(resid(cv), resid(sv));
            }
#pragma unroll
            for (int ni = 0; ni < 4; ++ni) {
                acc[mi][ni] = __builtin_amdgcn_mfma_f32_16x16x32_bf16(ah.s, bh[ni], acc[mi][ni], 0, 0, 0);
                acc[mi][ni] = __builtin_amdgcn_mfma_f32_16x16x32_bf16(ah.s, bl[ni], acc[mi][ni], 0, 0, 0);
                acc[mi][ni] = __builtin_amdgcn_mfma_f32_16x16x32_bf16(al.s, bh[ni], acc[mi][ni], 0, 0, 0);
            }
        }
    }

    // epilogue: gelu (tanh approx, matches jax.nn.gelu) + store
#pragma unroll
    for (int mi = 0; mi < 4; ++mi)
#pragma unroll
        for (int ni = 0; ni < 4; ++ni)
#pragma unroll
            for (int r = 0; r < 4; ++r) {
                int n = wr + mi * 16 + kg * 4 + r;
                int o = wc + ni * 16 + fr;
                float v = acc[mi][ni][r];
                float u = 0.7978845608028654f * (v + 0.044715f * v * v * v);
                float g = 0.5f * v * (1.0f + tanhf(u));
                hf[((size_t)(b << 15) + n0 + n) * 128 + o] = g;
            }
}

// ---------------- out projection
__global__ __launch_bounds__(256) void out_proj(const float* __restrict__ hf,
                                                const float* __restrict__ w,
                                                const float* __restrict__ bias,
                                                float* __restrict__ u) {
    int tid = threadIdx.x;
    int wv = tid >> 6, ln = tid & 63;
    size_t row = (size_t)blockIdx.x * 4 + wv;
    const float* hp = hf + row * Cc;
    float h0 = hp[ln], h1 = hp[ln + 64];
    float s0 = h0 * w[ln * 2 + 0] + h1 * w[(ln + 64) * 2 + 0];
    float s1 = h0 * w[ln * 2 + 1] + h1 * w[(ln + 64) * 2 + 1];
#pragma unroll
    for (int off = 32; off > 0; off >>= 1) {
        s0 += __shfl_down(s0, off);
        s1 += __shfl_down(s1, off);
    }
    if (ln == 0) {
        u[row * 2 + 0] = s0 + bias[0];
        u[row * 2 + 1] = s1 + bias[1];
    }
}

extern "C" void kernel_launch(void* const* d_in, const int* in_sizes, int n_in,
                              void* d_out, int out_size, void* d_ws, size_t ws_size,
                              hipStream_t stream) {
    const float* a        = (const float*)d_in[0];
    const float* x        = (const float*)d_in[1];
    const float* y        = (const float*)d_in[2];
    const float* fc_in_w  = (const float*)d_in[3];
    const float* fc_in_b  = (const float*)d_in[4];
    const float* freqs    = (const float*)d_in[5];
    const float* w_real   = (const float*)d_in[6];
    const float* w_imag   = (const float*)d_in[7];
    const float* fc_out_w = (const float*)d_in[8];
    const float* fc_out_b = (const float*)d_in[9];
    float* out = (float*)d_out;

    float*  ws    = (float*)d_ws;
    float*  hf    = ws;                                       // 8,388,608 floats
    float*  Spart = hf + (size_t)Bb * Nn * Cc;                // B*2*SKN*C*F = 8,388,608
    float*  S     = Spart + (size_t)Bb * 2 * SKN * Cc * Ff;   // 65,536
    uint_t* Gh    = (uint_t*)(S + (size_t)Bb * 2 * Cc * Ff);  // 32,768 dwords
    uint_t* Gl    = Gh + (size_t)Bb * Cc * Ff;                // 32,768 dwords

    in_proj<<<(Bb * Nn * Cc) / 256, 256, 0, stream>>>(a, fc_in_w, fc_in_b, hf);

    for (int l = 0; l < LL; ++l) {
        const float* k   = freqs  + (size_t)l * Ff * 3;
        const float* Wre = w_real + (size_t)l * Cc * Cc * Ff;
        const float* Wim = w_imag + (size_t)l * Cc * Cc * Ff;
        const float* pts = (l < LL - 1) ? x : y;

        fwd_mfma<<<dim3(SKN, Bb), 512, 0, stream>>>(hf, x, k, Spart);
        reduce_kernel<<<(Bb * 2 * Cc * Ff) / 256, 256, 0, stream>>>(Spart, S);
        mix_kernel<<<dim3(16, 4, Bb), 256, 0, stream>>>(S, Wre, Wim, Gh, Gl);
        inv_mfma<<<dim3(Nn / 128, Bb), 256, 0, stream>>>(Gh, Gl, pts, k, hf);
    }

    out_proj<<<(Bb * Nn) / 4, 256, 0, stream>>>(hf, fc_out_w, fc_out_b, out);
}